// Round 4
// baseline (414.070 us; speedup 1.0000x reference)
//
#include <hip/hip_runtime.h>
#include <math.h>

// Problem constants (B=4, S=4096, H=4096, E=64, top_k=8)
#define H_DIM  4096
#define E_NUM  64
#define N_TOK  16384          // B*S
#define TPB    64             // tokens per block
#define KC     64             // K chunk
#define NCHUNK (H_DIM / KC)   // 64
#define TOPK   8

// flat output layout: [probs (N_TOK*64)][indices (N_TOK*8)][gate (N_TOK*64)]
#define N_PROBS  (N_TOK * E_NUM)          // 1048576
#define N_IDX    (N_TOK * TOPK)           // 131072
#define OFF_IDX  N_PROBS
#define OFF_GATE (N_PROBS + N_IDX)        // 1179648

// pre-converted W image: per chunk, 3 bf16 arrays [64 expert][64 k] laid out
// exactly as the main kernel's LDS W tiles (XOR-swizzle baked in), so main-
// loop W staging is a straight 16-B copy.
#define W3_CHUNK_BYTES (3 * 64 * 64 * 2)          // 24576
#define W3_BYTES       (NCHUNK * W3_CHUNK_BYTES)  // 1572864

// v5: v4 + (a) 8 waves = 2/SIMD via in-block k-split-2 (MFMA blocks its wave;
// at 1 wave/SIMD v4 was serial: 24 MFMA x 32cyc + ~2000 VALU cvt per chunk =
// the measured ~160us). (b) W bf16 triple pre-converted once into d_ws ->
// main loop stages W with plain b128 copies (half the cvt VALU gone).
// Numerics identical to v4 (same RNE splits, same 6 products, same fp64 fold
// cadence; k-split chains are 48 MFMA-adds < v4's 96).

#define XH 0
#define XM 1
#define XL 2

typedef __attribute__((ext_vector_type(8)))  short short8;   // 8 bf16 = 4 VGPR
typedef __attribute__((ext_vector_type(16))) float f32x16;   // 32x32 acc

// RNE fp32 -> bf16, returning the bf16 bits and the exact fp32 remainder.
__device__ __forceinline__ unsigned short bf_split(float v, float& rem) {
  unsigned u  = __builtin_bit_cast(unsigned, v);
  unsigned hb = (u + 0x7FFFu + ((u >> 16) & 1u)) & 0xFFFF0000u;
  rem = v - __builtin_bit_cast(float, hb);   // exact (Sterbenz: same binade)
  return (unsigned short)(hb >> 16);
}
__device__ __forceinline__ unsigned short bf_rne(float v) {
  unsigned u = __builtin_bit_cast(unsigned, v);
  return (unsigned short)((u + 0x7FFFu + ((u >> 16) & 1u)) >> 16);
}

// ---- pre-kernel: W fp32 -> swizzled bf16 triple image in workspace --------
__global__ __launch_bounds__(256, 1)
void wconv_kernel(const float* __restrict__ W, unsigned short* __restrict__ w3) {
  const int c   = blockIdx.x;          // K chunk
  const int t   = threadIdx.x;
  const int r   = t >> 2;              // expert row 0..63
  const int kk0 = (t & 3) * 16;        // k offset within chunk
  const float* src = W + (size_t)r * H_DIM + c * KC + kk0;
  char* dst = (char*)w3 + (size_t)c * W3_CHUNK_BYTES;
  const int swz = (r & 7) << 4;
#pragma unroll
  for (int q = 0; q < 4; ++q) {        // 4 float4 = 16 elements
    const float4 v = *(const float4*)(src + 4 * q);
    const float f[4] = {v.x, v.y, v.z, v.w};
    unsigned short h[4], m[4], l[4];
#pragma unroll
    for (int i = 0; i < 4; ++i) {
      float r1, r2;
      h[i] = bf_split(f[i], r1);
      m[i] = bf_split(r1, r2);
      l[i] = bf_rne(r2);
    }
    const int kb = 2 * (kk0 + 4 * q);  // byte offset of these 4 bf16 in the row
    *(ushort4*)(dst + 0 * 8192 + r * 128 + (kb ^ swz)) = ushort4{h[0], h[1], h[2], h[3]};
    *(ushort4*)(dst + 1 * 8192 + r * 128 + (kb ^ swz)) = ushort4{m[0], m[1], m[2], m[3]};
    *(ushort4*)(dst + 2 * 8192 + r * 128 + (kb ^ swz)) = ushort4{l[0], l[1], l[2], l[3]};
  }
}

// ---- main kernel ----------------------------------------------------------
template <bool PREW>
__global__ __launch_bounds__(512, 2)
void gating_kernel(const float* __restrict__ x, const float* __restrict__ W,
                   float* __restrict__ out, const unsigned short* __restrict__ w3) {
  // xs/ws: 3 bf16 arrays [64 rows][64 k] each, double-buffered = 96 KB.
  // Rows are 128 B; byte ^= (row&7)<<4 keeps b128 frag reads at the hardware
  // minimum (G4). Overlays: fp64 cross-group dump @ +32 KB, epilogue lg @ 0.
  __shared__ union {
    struct { unsigned short xs[2][3][64][64]; unsigned short ws_[2][3][64][64]; } t; // 96 KB
    struct { float pad[8192]; double dump[4][16][64]; } r;   // 32 KB @ +32 KB
    float lg[TPB][E_NUM + 1];                                // 16.6 KB
  } u;

  const int tid  = threadIdx.x;
  const int tok0 = blockIdx.x * TPB;
  const int lane = tid & 63;
  const int wid  = tid >> 6;            // 0..7
  const int g    = wid >> 2;            // k-half group: kt {0,1} or {2,3}
  const int sub  = wid & 3;             // output tile id
  const int wm   = sub >> 1;            // token half  (32 tokens)
  const int wn   = sub & 1;             // expert half (32 experts)
  const int l31  = lane & 31;
  const int arow = 32 * wm + l31;       // token row for A frags
  const int brow = 32 * wn + l31;       // expert row for B frags
  const int kloff = 16 * (lane >> 5);   // byte offset of this lane's k-group

  const float* xg = x + (size_t)tok0 * H_DIM;
  unsigned short* xbase = &u.t.xs[0][0][0][0];   // buffer stride 3*8192 B
  unsigned short* wbase = &u.t.ws_[0][0][0][0];

  auto sw = [](unsigned short* base, int row, int kbyte) -> void* {
    return (char*)base + row * 128 + (kbyte ^ ((row & 7) << 4));
  };

  float4 xr[2], wr[2];
  short8 wcp[3];

  // x tile 64x64 fp32 = 1024 float4 / 512 threads = 2 each.
  auto gloadX = [&](int kb) {
#pragma unroll
    for (int p = 0; p < 2; ++p) {
      const int f4  = tid + 512 * p;
      const int row = f4 >> 4;
      const int kq  = f4 & 15;
      xr[p] = *(const float4*)(xg + (size_t)row * H_DIM + kb + 4 * kq);
    }
  };
  // W: either copy the pre-converted image (3x16B per thread) or load fp32.
  auto gloadW = [&](int c) {
    if (PREW) {
      const char* src = (const char*)w3 + (size_t)c * W3_CHUNK_BYTES + tid * 16;
#pragma unroll
      for (int s = 0; s < 3; ++s)
        wcp[s] = *(const short8*)(src + s * 8192);
    } else {
      const int kb = c * KC;
#pragma unroll
      for (int p = 0; p < 2; ++p) {
        const int f4  = tid + 512 * p;
        const int row = f4 >> 4;
        const int kq  = f4 & 15;
        wr[p] = *(const float4*)(W + (size_t)row * H_DIM + kb + 4 * kq);
      }
    }
  };

  // split fp32x4 -> 3x bf16x4, swizzled b64 stores (verified v4 path)
  auto cvt_store = [&](const float4& v, unsigned short* base, int row, int kbyte) {
    const float f[4] = {v.x, v.y, v.z, v.w};
    unsigned short h[4], m[4], l[4];
#pragma unroll
    for (int i = 0; i < 4; ++i) {
      float r1, r2;
      h[i] = bf_split(f[i], r1);
      m[i] = bf_split(r1, r2);
      l[i] = bf_rne(r2);
    }
    *(ushort4*)sw(base + 0 * 4096, row, kbyte) = ushort4{h[0], h[1], h[2], h[3]};
    *(ushort4*)sw(base + 1 * 4096, row, kbyte) = ushort4{m[0], m[1], m[2], m[3]};
    *(ushort4*)sw(base + 2 * 4096, row, kbyte) = ushort4{l[0], l[1], l[2], l[3]};
  };

  auto sstore = [&](int b) {
    unsigned short* xb = xbase + b * 3 * 4096;
    unsigned short* wb = wbase + b * 3 * 4096;
#pragma unroll
    for (int p = 0; p < 2; ++p) {
      const int f4    = tid + 512 * p;
      const int row   = f4 >> 4;
      const int kbyte = (f4 & 15) * 8;
      cvt_store(xr[p], xb, row, kbyte);
      if (!PREW) cvt_store(wr[p], wb, row, kbyte);
    }
    if (PREW) {
      char* dst = (char*)wb + tid * 16;   // linear: swizzle baked into image
#pragma unroll
      for (int s = 0; s < 3; ++s)
        *(short8*)(dst + s * 8192) = wcp[s];
    }
  };

  gloadX(0);
  gloadW(0);
  sstore(0);
  __syncthreads();

  // Two interleaved fp32 acc chains, fp64 fold every 4 chunks (48-add chains
  // with the k-split -> same error class as v4).
  f32x16 accA, accB;
  double accd[16];
#pragma unroll
  for (int r = 0; r < 16; ++r) { accA[r] = 0.f; accB[r] = 0.f; accd[r] = 0.0; }

  for (int c = 0; c < NCHUNK; ++c) {
    if (c + 1 < NCHUNK) { gloadX((c + 1) * KC); gloadW(c + 1); }
    const int b = c & 1;
    unsigned short* xb = xbase + b * 3 * 4096;
    unsigned short* wb = wbase + b * 3 * 4096;

#pragma unroll
    for (int j = 0; j < 2; ++j) {              // this group's 2 k-tiles of 16
      const int kb = (2 * g + j) * 32 + kloff;
      const short8 ah = *(const short8*)sw(xb + 0 * 4096, arow, kb);
      const short8 am = *(const short8*)sw(xb + 1 * 4096, arow, kb);
      const short8 al = *(const short8*)sw(xb + 2 * 4096, arow, kb);
      const short8 bh = *(const short8*)sw(wb + 0 * 4096, brow, kb);
      const short8 bm = *(const short8*)sw(wb + 1 * 4096, brow, kb);
      const short8 bl = *(const short8*)sw(wb + 2 * 4096, brow, kb);
      accA = __builtin_amdgcn_mfma_f32_32x32x16_bf16(ah, bh, accA, 0, 0, 0);
      accB = __builtin_amdgcn_mfma_f32_32x32x16_bf16(am, bm, accB, 0, 0, 0);
      accA = __builtin_amdgcn_mfma_f32_32x32x16_bf16(am, bh, accA, 0, 0, 0);
      accB = __builtin_amdgcn_mfma_f32_32x32x16_bf16(ah, bm, accB, 0, 0, 0);
      accA = __builtin_amdgcn_mfma_f32_32x32x16_bf16(al, bh, accA, 0, 0, 0);
      accB = __builtin_amdgcn_mfma_f32_32x32x16_bf16(ah, bl, accB, 0, 0, 0);
    }

    if ((c & 3) == 3) {
#pragma unroll
      for (int r = 0; r < 16; ++r) {
        accd[r] += (double)accA[r] + (double)accB[r];
        accA[r] = 0.f; accB[r] = 0.f;
      }
    }

    if (c + 1 < NCHUNK) {
      // stage(c+1) writes buffer (c+1)&1, last read by compute(c-1) which
      // finished before the previous barrier -> one barrier per chunk.
      sstore((c + 1) & 1);
      __syncthreads();
    }
  }
  __syncthreads();   // all frag reads done before the dump overlays the tiles

  // cross-k-group fp64 reduce: g1 dumps, g0 adds. [tile][reg][lane] -> lanes
  // consecutive 8B words = 2-way bank aliasing = free.
  if (g == 1) {
#pragma unroll
    for (int r = 0; r < 16; ++r) u.r.dump[sub][r][lane] = accd[r];
  }
  __syncthreads();

  if (g == 0) {
    // C/D layout (HW-verified m74/m101): col = lane&31,
    // row = (reg&3) + 8*(reg>>2) + 4*(lane>>5).
    const int rb = 4 * (lane >> 5);
    float* gate = out + OFF_GATE;
#pragma unroll
    for (int q = 0; q < 4; ++q)
#pragma unroll
      for (int j = 0; j < 4; ++j) {
        const int reg   = 4 * q + j;
        const int row32 = j + 8 * q + rb;
        const float v   = (float)(accd[reg] + u.r.dump[sub][reg][lane]);
        const int trow  = 32 * wm + row32;
        const int e     = 32 * wn + l31;
        gate[(size_t)(tok0 + trow) * E_NUM + e] = v;   // coalesced 128B/half-wave
        u.lg[trow][e] = v;    // lg (@0..16.6KB) disjoint from dump (@32KB)
      }
  }
  __syncthreads();

  // Phase 2: one thread per token — verbatim from the verified kernel
  // (strict > == jax lowest-index tie-break).
  if (tid < TPB) {
    const int t = tid;
    float vals[TOPK];
    int   idxs[TOPK];
#pragma unroll
    for (int p = 0; p < TOPK; ++p) {
      float best = -INFINITY;
      int   bi   = 0;
      for (int e = 0; e < E_NUM; ++e) {
        const float v = u.lg[t][e];
        if (v > best) { best = v; bi = e; }
      }
      vals[p] = best;
      idxs[p] = bi;
      u.lg[t][bi] = -INFINITY;
    }
    const float m = vals[0];
    float s = 0.f, pr[TOPK];
#pragma unroll
    for (int p = 0; p < TOPK; ++p) { pr[p] = __expf(vals[p] - m); s += pr[p]; }
    const float inv = 1.0f / s;
    for (int e = 0; e < E_NUM; ++e) u.lg[t][e] = 0.f;
#pragma unroll
    for (int p = 0; p < TOPK; ++p) u.lg[t][idxs[p]] = pr[p] * inv;

    float* oidx = out + OFF_IDX + (size_t)(tok0 + t) * TOPK;
#pragma unroll
    for (int p = 0; p < TOPK; ++p) oidx[p] = (float)idxs[p];
  }
  __syncthreads();

  // coalesced writeback of the sparse_probs rows (512 threads x 8)
  float* oprob = out + (size_t)tok0 * E_NUM;
#pragma unroll
  for (int p = 0; p < 8; ++p) {
    const int f = tid + 512 * p;
    oprob[f] = u.lg[f >> 6][f & 63];
  }
}

extern "C" void kernel_launch(void* const* d_in, const int* in_sizes, int n_in,
                              void* d_out, int out_size, void* d_ws, size_t ws_size,
                              hipStream_t stream) {
  const float* x = (const float*)d_in[0];
  const float* W = (const float*)d_in[1];
  float* out = (float*)d_out;
  if (ws_size >= (size_t)W3_BYTES && d_ws != nullptr) {
    unsigned short* w3 = (unsigned short*)d_ws;
    wconv_kernel<<<dim3(NCHUNK), dim3(256), 0, stream>>>(W, w3);
    gating_kernel<true><<<dim3(N_TOK / TPB), dim3(512), 0, stream>>>(x, W, out, w3);
  } else {
    gating_kernel<false><<<dim3(N_TOK / TPB), dim3(512), 0, stream>>>(x, W, out, nullptr);
  }
}